// Round 13
// baseline (36.754 us; speedup 1.0000x reference)
//
#include <hip/hip_runtime.h>

// Grouped conv1d over W + roll(+1) along H, bf16 MFMA 16x16x32.
// x: (128, 48, 28, 28) f32, channel = g*24+ci
// w: (24, 96, 7) f32, w[ci][o][k], shared across the 2 groups
// out: (128, 192, 28, 28) f32, channel = g*96+o
//
// R13: staging moved OUT of the hot kernel. xpose_kernel writes
// xbf2[b][g][hd][p][ci] bf16 (12.4MB) = the exact LDS image per block,
// output-row-ordered (roll pre-absorbed: src row = (hd-1) mod 28).
// conv kernel stages its 6912B slice with SEVEN global_load_lds width=16
// instructions (no VGPR roundtrip, no cvt, no index math), then runs the
// R10-proven compute/epilogue. R12 exonerated LDS traffic + MFMA chains;
// the ~28us convoy = staging VALU/latency in series with store drain.
//
// GEMM per tile: M=112 (4 output rows x 28 W), N=96, K=168 pad 192.
// k-permutation (A and B must match): q = ks*4+kgrp (0..23);
//   q<21: k=q/3, ci=(q%3)*8+j ; q>=21: zero (B side).

typedef __attribute__((ext_vector_type(8))) short short8;
typedef __attribute__((ext_vector_type(4))) float float4v;

#define B_     128
#define H_     28
#define W_     28
#define CIN_   24
#define COUT_  96
#define K_     7
#define KSTEPS 6
#define NT_    6
#define MT_    7
#define HW_    784
#define WFBYTES   36864        // 36 frags * 64 lanes * 16B
#define XBFDWORDS 3096576      // 128*2*28*36*12 packed bf16 pairs
#define XBFBYTES  (XBFDWORDS * 4)

// float -> bf16 bits, RNE
static __device__ __forceinline__ short f2bf(float f) {
    union { float f; unsigned u; } v; v.f = f;
    return (short)((v.u + 0x7fffu + ((v.u >> 16) & 1u)) >> 16);
}
// packed 2x f32 -> bf16x2, one instruction
static __device__ __forceinline__ unsigned cvt_pk_bf16(float a, float b) {
    unsigned r;
    asm("v_cvt_pk_bf16_f32 %0, %1, %2" : "=v"(r) : "v"(a), "v"(b));
    return r;
}

static __device__ __forceinline__ void gload_lds16(const void* g, void* l) {
    __builtin_amdgcn_global_load_lds(
        (const __attribute__((address_space(1))) unsigned*)g,
        (__attribute__((address_space(3))) unsigned*)l, 16, 0, 0);
}

// ---- wfrag body (shared): B-frag (16x16x32) lane l holds
// B[hw=(l>>4)*8+j][col=l&15], j=0..7, with the permuted k-axis.
static __device__ __forceinline__ void wfrag_build(const float* __restrict__ w,
                                                   short8* __restrict__ wf,
                                                   int idx, int lane) {
    const int ks = idx / 6, nt = idx - ks * 6;
    const int c  = nt * 16 + (lane & 15);
    const int q  = ks * 4 + (lane >> 4);
    short8 v;
    if (q < 21) {
        const int k   = (q * 11) >> 5;    // q/3 for q in 0..23
        const int ci0 = (q - 3 * k) * 8;
#pragma unroll
        for (int j = 0; j < 8; ++j)
            v[j] = f2bf(w[(ci0 + j) * (COUT_ * K_) + c * K_ + k]);
    } else {
#pragma unroll
        for (int j = 0; j < 8; ++j) v[j] = 0;
    }
    wf[idx * 64 + lane] = v;
}

// ---- pre-kernel: x (f32) -> xbf2 bf16 [bg][hd][p][ci-pair], roll absorbed.
// Writes coalesced (cp fastest); reads L3-hot scattered. Also builds wf.
__global__ __launch_bounds__(256)
void xpose_kernel(const float* __restrict__ x, unsigned* __restrict__ xbf,
                  const float* __restrict__ w, short8* __restrict__ wf) {
    const int i  = blockIdx.x * 256 + threadIdx.x;   // < 3096576 exactly
    const int cp = i % 12;
    const int r1 = i / 12;
    const int p  = r1 % 36;
    const int r2 = r1 / 36;
    const int hd = r2 % 28;
    const int bg = r2 / 28;
    const int g  = bg & 1;
    const int b  = bg >> 1;
    const int rsrc = hd ? hd - 1 : 27;               // (hd-1) mod 28
    const int ws = p - 3;
    float v0 = 0.0f, v1 = 0.0f;
    if (ws >= 0 && ws < W_) {
        const size_t base = ((size_t)(b * 48 + g * CIN_ + 2 * cp) * H_ + rsrc) * W_ + ws;
        v0 = x[base];
        v1 = x[base + (size_t)HW_];
    }
    xbf[i] = cvt_pk_bf16(v0, v1);

    if (blockIdx.x < 36 && threadIdx.x < 64)
        wfrag_build(w, wf, blockIdx.x, threadIdx.x);
}

// ---- hot kernel: DMA-stage 6912B slice, 1 barrier, R10 compute/epilogue.
__global__ __launch_bounds__(384, 6)
void conv_mfma_kernel(const unsigned* __restrict__ xbf,
                      const short8* __restrict__ wfg,
                      float* __restrict__ out) {
    const int bid = blockIdx.x;           // (b*2+g)*7 + ht
    const int ht  = bid % 7;
    const int bg  = bid / 7;
    const int g   = bg & 1;
    const int b   = bg >> 1;
    const int tid  = threadIdx.x;
    const int lane = tid & 63;
    const int nt   = tid >> 6;            // wave = N-tile, 0..5
    const int cgrp = lane & 15;
    const int kgrp = lane >> 4;

    __shared__ __align__(16) short xs[4 * 36 * 24];   // 6912 B

    // Stage: contiguous 6912B slice of xbf2 -> LDS via global_load_lds.
    // Wave wv copies [wv*1024, wv*1024+1024); wave 0 adds the 768B tail.
    const char* slice = (const char*)xbf + (size_t)(bg * 28 + 4 * ht) * 1728;
    gload_lds16(slice + nt * 1024 + lane * 16, (char*)xs + nt * 1024);
    if (nt == 0 && lane < 48)
        gload_lds16(slice + 6144 + lane * 16, (char*)xs + 6144);

    // B fragments: 6 L2-hot dwordx4 -> 24 VGPR (overlaps the DMA)
    short8 br[KSTEPS];
#pragma unroll
    for (int ks = 0; ks < KSTEPS; ++ks)
        br[ks] = wfg[(ks * NT_ + nt) * 64 + lane];

    __syncthreads();   // drains vmcnt (global_load_lds) before LDS reads

    // Per-lane k-step LDS offsets (A side of the shared k permutation)
    int koff[KSTEPS];
#pragma unroll
    for (int ks = 0; ks < KSTEPS; ++ks) {
        const int q   = ks * 4 + kgrp;
        const int k   = (q * 11) >> 5;
        const int ci0 = (q - 3 * k) * 8;
        koff[ks] = k * 24 + ci0;
    }

    const int c_out = nt * 16 + cgrp;
    float* cbase = out + ((size_t)(b * 192 + g * COUT_ + c_out)) * HW_;

#pragma unroll
    for (int mt = 0; mt < MT_; ++mt) {
        const int mA = mt * 16 + cgrp;
        const int hA = mA / 28;
        const int tA = mA - hA * 28;
        const int abase = (hA * 36 + tA) * 24;
        float4v acc = (float4v)(0.0f);
#pragma unroll
        for (int ks = 0; ks < KSTEPS; ++ks) {
            const short8 a = *(const short8*)&xs[abase + koff[ks]];
            acc = __builtin_amdgcn_mfma_f32_16x16x32_bf16(a, br[ks], acc, 0, 0, 0);
        }
        // D-quad j=0..3 = 4 consecutive t in one h-row (m0 % 4 == 0, 4 | 28)
        const int m0 = mt * 16 + kgrp * 4;
        const int hl = m0 / 28;
        const int t0 = m0 - hl * 28;
        const int hd = 4 * ht + hl;       // output row (roll absorbed in xbf2)
        float4 v; v.x = acc[0]; v.y = acc[1]; v.z = acc[2]; v.w = acc[3];
        *(float4*)&cbase[hd * W_ + t0] = v;
    }
}

// ---- fallback (R10 path) if d_ws is too small for xbf2 ----
__global__ __launch_bounds__(64)
void wfrag_kernel(const float* __restrict__ w, short8* __restrict__ wf) {
    wfrag_build(w, wf, blockIdx.x, threadIdx.x);
}

__global__ __launch_bounds__(384, 6)
void conv_fallback_kernel(const float* __restrict__ x,
                          const short8* __restrict__ wfg,
                          float* __restrict__ out) {
    const int bid = blockIdx.x;
    const int ht  = bid % 7;
    const int bg  = bid / 7;
    const int g   = bg & 1;
    const int b   = bg >> 1;
    const int tid  = threadIdx.x;
    const int lane = tid & 63;
    const int nt   = tid >> 6;
    const int cgrp = lane & 15;
    const int kgrp = lane >> 4;

    __shared__ __align__(16) short xs[4 * 36 * 24];

    float v0r[5], v1r[5];
#pragma unroll
    for (int it = 0; it < 5; ++it) {
        const int idx = tid + it * 384;
        if (idx < 1728) {
            const int p  = idx % 36;
            const int r  = idx / 36;
            const int cp = r % 12;
            const int hl = r / 12;
            const int ws = p - 3;
            const int rsrc = (4 * ht + hl + 27) % 28;
            float a0 = 0.0f, a1 = 0.0f;
            if (ws >= 0 && ws < W_) {
                const size_t base =
                    ((size_t)(b * 48 + g * CIN_ + cp * 2) * H_ + rsrc) * W_ + ws;
                a0 = x[base];
                a1 = x[base + (size_t)HW_];
            }
            v0r[it] = a0; v1r[it] = a1;
        }
    }
    short8 br[KSTEPS];
#pragma unroll
    for (int ks = 0; ks < KSTEPS; ++ks)
        br[ks] = wfg[(ks * NT_ + nt) * 64 + lane];
#pragma unroll
    for (int it = 0; it < 5; ++it) {
        const int idx = tid + it * 384;
        if (idx < 1728) {
            const int p  = idx % 36;
            const int r  = idx / 36;
            const int cp = r % 12;
            const int hl = r / 12;
            ((unsigned*)xs)[(hl * 36 + p) * 12 + cp] = cvt_pk_bf16(v0r[it], v1r[it]);
        }
    }
    __syncthreads();

    int koff[KSTEPS];
#pragma unroll
    for (int ks = 0; ks < KSTEPS; ++ks) {
        const int q   = ks * 4 + kgrp;
        const int k   = (q * 11) >> 5;
        const int ci0 = (q - 3 * k) * 8;
        koff[ks] = k * 24 + ci0;
    }
    const int c_out = nt * 16 + cgrp;
    float* cbase = out + ((size_t)(b * 192 + g * COUT_ + c_out)) * HW_;
#pragma unroll
    for (int mt = 0; mt < MT_; ++mt) {
        const int mA = mt * 16 + cgrp;
        const int hA = mA / 28;
        const int tA = mA - hA * 28;
        const int abase = (hA * 36 + tA) * 24;
        float4v acc = (float4v)(0.0f);
#pragma unroll
        for (int ks = 0; ks < KSTEPS; ++ks) {
            const short8 a = *(const short8*)&xs[abase + koff[ks]];
            acc = __builtin_amdgcn_mfma_f32_16x16x32_bf16(a, br[ks], acc, 0, 0, 0);
        }
        const int m0 = mt * 16 + kgrp * 4;
        const int hl = m0 / 28;
        const int t0 = m0 - hl * 28;
        const int hd = 4 * ht + hl;
        float4 v; v.x = acc[0]; v.y = acc[1]; v.z = acc[2]; v.w = acc[3];
        *(float4*)&cbase[hd * W_ + t0] = v;
    }
}

extern "C" void kernel_launch(void* const* d_in, const int* in_sizes, int n_in,
                              void* d_out, int out_size, void* d_ws, size_t ws_size,
                              hipStream_t stream) {
    const float* x = (const float*)d_in[0];
    const float* w = (const float*)d_in[1];
    float* out = (float*)d_out;
    short8*   wf  = (short8*)d_ws;                       // [0, 36864)
    unsigned* xbf = (unsigned*)((char*)d_ws + WFBYTES);  // [36864, +12.4MB)

    if (ws_size >= (size_t)WFBYTES + XBFBYTES) {
        xpose_kernel<<<XBFDWORDS / 256, 256, 0, stream>>>(x, xbf, w, wf);
        conv_mfma_kernel<<<B_ * 2 * 7, 384, 0, stream>>>(xbf, wf, out);
    } else {
        wfrag_kernel<<<36, 64, 0, stream>>>(w, wf);
        conv_fallback_kernel<<<B_ * 2 * 7, 384, 0, stream>>>(x, wf, out);
    }
}

// Round 14
// 30.324 us; speedup vs baseline: 1.2120x; 1.2120x over previous
//
#include <hip/hip_runtime.h>

// Grouped conv1d over W + roll(+1) along H, bf16 MFMA 16x16x32.
// x: (128, 48, 28, 28) f32, channel = g*24+ci
// w: (24, 96, 7) f32, w[ci][o][k], shared across the 2 groups
// out: (128, 192, 28, 28) f32, channel = g*96+o
//
// R14: DRAM-burst theory. One block per (b,g): stage the WHOLE 24ch x 28row
// input slice once (48.4KB LDS, one barrier), then each wave owns 16 output
// channels and walks all 784 positions in 49 M-tiles. Store offset = cbase +
// mt*16 + kgrp*4 -> each channel's 3136B is ONE sequential walk (vs 448B
// isolated runs in R6-R13), per-block writes = one contiguous 301KB region.
// No inter-tile barriers; waves free-run after staging.
//
// GEMM: M=784 (28 output rows x 28 W), N=96, K=168 pad 192.
// k-permutation (A and B must match): q = ks*4+kgrp (0..23);
//   q<21: k=q/3, ci=(q%3)*8+j ; q>=21: zero (B side).
// Roll absorbed in staging: xs row h holds source row (h-1) mod 28.

typedef __attribute__((ext_vector_type(8))) short short8;
typedef __attribute__((ext_vector_type(4))) float float4v;

#define B_     128
#define H_     28
#define W_     28
#define CIN_   24
#define COUT_  96
#define K_     7
#define KSTEPS 6
#define NT_    6
#define HW_    784
#define NDW    12096   // 28*36*12 staged packed dwords per block

// float -> bf16 bits, RNE (cold path: wfrag kernel only)
static __device__ __forceinline__ short f2bf(float f) {
    union { float f; unsigned u; } v; v.f = f;
    return (short)((v.u + 0x7fffu + ((v.u >> 16) & 1u)) >> 16);
}
// packed 2x f32 -> bf16x2, one instruction
static __device__ __forceinline__ unsigned cvt_pk_bf16(float a, float b) {
    unsigned r;
    asm("v_cvt_pk_bf16_f32 %0, %1, %2" : "=v"(r) : "v"(a), "v"(b));
    return r;
}

// Pre-pack weights into B-fragment order with the permuted k-axis.
// B-frag (16x16x32): lane l holds B[hw=(l>>4)*8+j][col=l&15], j=0..7
__global__ __launch_bounds__(64)
void wfrag_kernel(const float* __restrict__ w, short8* __restrict__ wf) {
    const int idx  = blockIdx.x;          // 0..35 = ks*6 + nt
    const int ks   = idx / 6, nt = idx - ks * 6;
    const int lane = threadIdx.x;
    const int c    = nt * 16 + (lane & 15);
    const int q    = ks * 4 + (lane >> 4);
    short8 v;
    if (q < 21) {
        const int k   = (q * 11) >> 5;    // q/3 for q in 0..23
        const int ci0 = (q - 3 * k) * 8;
#pragma unroll
        for (int j = 0; j < 8; ++j)
            v[j] = f2bf(w[(ci0 + j) * (COUT_ * K_) + c * K_ + k]);
    } else {
#pragma unroll
        for (int j = 0; j < 8; ++j) v[j] = 0;   // zero-pad K (A garbage harmless)
    }
    wf[idx * 64 + lane] = v;
}

__global__ __launch_bounds__(384)
void conv_mfma_kernel(const float* __restrict__ x,
                      const short8* __restrict__ wfg,
                      float* __restrict__ out) {
    const int bg  = blockIdx.x;           // 256 = b*2 + g
    const int g   = bg & 1;
    const int b   = bg >> 1;
    const int tid  = threadIdx.x;
    const int lane = tid & 63;
    const int nt   = tid >> 6;            // wave = N-tile (16 channels), 0..5
    const int cgrp = lane & 15;
    const int kgrp = lane >> 4;

    // xs[h][p][ci] bf16: 28 rows x 36 padded positions x 24 ch. 48384 B.
    __shared__ __align__(16) short xs[28 * 36 * 24];

    // ---- B fragments: 6 L2-hot dwordx4 -> 24 VGPR (issued first)
    short8 br[KSTEPS];
#pragma unroll
    for (int ks = 0; ks < KSTEPS; ++ks)
        br[ks] = wfg[(ks * NT_ + nt) * 64 + lane];

    // ---- stage whole (b,g) slice: 12096 packed dwords, 4 chunks x 8 deep
    for (int ch = 0; ch < 4; ++ch) {
        float v0r[8], v1r[8];
#pragma unroll
        for (int it = 0; it < 8; ++it) {
            const int idx = tid + (ch * 8 + it) * 384;
            if (idx < NDW) {
                const int p  = idx % 36;
                const int r  = idx / 36;
                const int cp = r % 12;
                const int h  = r / 12;            // output row 0..27
                const int ws = p - 3;
                const int rsrc = h ? h - 1 : 27;  // roll(+1) absorbed
                float a0 = 0.0f, a1 = 0.0f;
                if (ws >= 0 && ws < W_) {
                    const size_t base =
                        ((size_t)(b * 48 + g * CIN_ + cp * 2) * H_ + rsrc) * W_ + ws;
                    a0 = x[base];
                    a1 = x[base + (size_t)HW_];
                }
                v0r[it] = a0; v1r[it] = a1;
            }
        }
#pragma unroll
        for (int it = 0; it < 8; ++it) {
            const int idx = tid + (ch * 8 + it) * 384;
            if (idx < NDW) {
                const int p  = idx % 36;
                const int r  = idx / 36;
                const int cp = r % 12;
                const int h  = r / 12;
                ((unsigned*)xs)[(h * 36 + p) * 12 + cp] = cvt_pk_bf16(v0r[it], v1r[it]);
            }
        }
    }
    __syncthreads();   // the only barrier; waves free-run after this

    // Per-lane k-step LDS offsets (A side of the shared k permutation)
    int koff[KSTEPS];
#pragma unroll
    for (int ks = 0; ks < KSTEPS; ++ks) {
        const int q   = ks * 4 + kgrp;
        const int k   = (q * 11) >> 5;
        const int ci0 = (q - 3 * k) * 8;
        koff[ks] = k * 24 + ci0;          // shorts; byte = k*48 + {0,16,32}
    }

    const int c_out = nt * 16 + cgrp;
    float* cbase = out + ((size_t)(b * 192 + g * COUT_ + c_out)) * HW_;

    // M-walk: 49 tiles of 16 positions; store offset = mt*16 + kgrp*4
    // (pure sequential per channel; 7 mt = exactly 4 h-rows)
#pragma unroll 7
    for (int mt = 0; mt < 49; ++mt) {
        const int mA = mt * 16 + cgrp;    // 0..783 (output position)
        const int hA = mA / 28;
        const int tA = mA - hA * 28;
        const int abase = (hA * 36 + tA) * 24;
        float4v acc = (float4v)(0.0f);
#pragma unroll
        for (int ks = 0; ks < KSTEPS; ++ks) {
            const short8 a = *(const short8*)&xs[abase + koff[ks]];
            acc = __builtin_amdgcn_mfma_f32_16x16x32_bf16(a, br[ks], acc, 0, 0, 0);
        }
        float4 v; v.x = acc[0]; v.y = acc[1]; v.z = acc[2]; v.w = acc[3];
        *(float4*)&cbase[mt * 16 + kgrp * 4] = v;
    }
}

extern "C" void kernel_launch(void* const* d_in, const int* in_sizes, int n_in,
                              void* d_out, int out_size, void* d_ws, size_t ws_size,
                              hipStream_t stream) {
    const float* x = (const float*)d_in[0];
    const float* w = (const float*)d_in[1];
    float* out = (float*)d_out;
    short8* wf = (short8*)d_ws;           // 36*64*16B = 36864 B

    wfrag_kernel<<<36, 64, 0, stream>>>(w, wf);
    conv_mfma_kernel<<<B_ * 2, 384, 0, stream>>>(x, wf, out);
}